// Round 2
// baseline (60.793 us; speedup 1.0000x reference)
//
#include <hip/hip_runtime.h>

#define NB 8
#define NC 64
#define NH 256
#define NW 256
#define HW (NH*NW)
#define NFH 64
#define NFW 64
#define FHW (NFH*NFW)
#define NS 256
#define PPB 1024          // pixels per block in main kernel
#define BLKS_PER_IMG (HW / PPB)   // 64

// ---------------- K1: feature channel-mean + zero accumulators ----------------
__global__ void fmean_zero_k(const float* __restrict__ feature,
                             float* __restrict__ fmean,
                             float* __restrict__ sum1,
                             float* __restrict__ sum2,
                             unsigned* __restrict__ cnt) {
  if (blockIdx.x < 128) {
    int idx = blockIdx.x * 256 + threadIdx.x;   // 0..32767  (= NB*FHW)
    int b  = idx >> 12;                         // / 4096
    int fp = idx & 4095;
    const float* src = feature + (size_t)b * NC * FHW + fp;
    float a = 0.f;
    #pragma unroll
    for (int c = 0; c < NC; ++c) a += src[(size_t)c * FHW];
    fmean[idx] = a * (1.0f / NC);
  } else {
    // one block zeros the segment accumulators
    for (int i = threadIdx.x; i < NB * NS; i += 256) {
      sum1[i] = 0.f; sum2[i] = 0.f; cnt[i] = 0u;
    }
  }
}

// ---------------- K2: streaming channel-mean of input + bilinear feat + LDS histogram ----------------
__global__ __launch_bounds__(256) void
main_k(const float* __restrict__ input,
       const int* __restrict__ sp,          // int32 ids (harness converts integers to int32)
       const float* __restrict__ fmean,
       float* __restrict__ sum1,
       float* __restrict__ sum2,
       unsigned* __restrict__ cnt) {
  __shared__ float s_f[FHW];          // 16 KB: per-image low-res channel-mean map
  __shared__ float s_sum1[NS];
  __shared__ float s_sum2[NS];
  __shared__ unsigned s_cnt[NS];

  const int b     = blockIdx.x >> 6;            // / BLKS_PER_IMG
  const int pbase = (blockIdx.x & (BLKS_PER_IMG - 1)) * PPB;
  const int tid   = threadIdx.x;

  const float* fsrc = fmean + (size_t)b * FHW;
  for (int i = tid; i < FHW; i += 256) s_f[i] = fsrc[i];
  s_sum1[tid] = 0.f; s_sum2[tid] = 0.f; s_cnt[tid] = 0u;
  __syncthreads();

  const int p0 = pbase + tid * 4;               // 4 consecutive pixels per thread
  const float* ibase = input + (size_t)b * NC * HW + p0;

  float4 acc = make_float4(0.f, 0.f, 0.f, 0.f);
  #pragma unroll 8
  for (int c = 0; c < NC; ++c) {
    float4 v = *reinterpret_cast<const float4*>(ibase + (size_t)c * HW);
    acc.x += v.x; acc.y += v.y; acc.z += v.z; acc.w += v.w;
  }
  const float inv_c = 1.0f / NC;
  float px[4] = {acc.x * inv_c, acc.y * inv_c, acc.z * inv_c, acc.w * inv_c};

  // sp ids: int32, 4 consecutive -> one int4 load
  int4 idv = *reinterpret_cast<const int4*>(sp + (size_t)b * HW + p0);
  int ids[4] = {idv.x, idv.y, idv.z, idv.w};

  // bilinear sample of fmean at each pixel (align_corners=True grid)
  #pragma unroll
  for (int i = 0; i < 4; ++i) {
    const int p = p0 + i;
    const int h = p >> 8;
    const int w = p & 255;
    // exact at integer sample points: (h*63)/255 in double
    double yd = (double)(h * (NFH - 1)) / (double)(NH - 1);
    double xd = (double)(w * (NFW - 1)) / (double)(NW - 1);
    int y0 = (int)yd;
    int x0 = (int)xd;
    float wy = (float)(yd - (double)y0);
    float wx = (float)(xd - (double)x0);
    int y1 = min(y0 + 1, NFH - 1);
    int x1 = min(x0 + 1, NFW - 1);
    float f00 = s_f[y0 * NFW + x0], f01 = s_f[y0 * NFW + x1];
    float f10 = s_f[y1 * NFW + x0], f11 = s_f[y1 * NFW + x1];
    float fv = (f00 * (1.f - wx) + f01 * wx) * (1.f - wy)
             + (f10 * (1.f - wx) + f11 * wx) * wy;

    atomicAdd(&s_sum1[ids[i]], px[i]);
    atomicAdd(&s_sum2[ids[i]], fv);
    atomicAdd(&s_cnt[ids[i]], 1u);
  }
  __syncthreads();

  // flush block-local histogram (tid == segment id)
  atomicAdd(&sum1[b * NS + tid], s_sum1[tid]);
  atomicAdd(&sum2[b * NS + tid], s_sum2[tid]);
  atomicAdd(&cnt[b * NS + tid], s_cnt[tid]);
}

// ---------------- K3: per-image segment means + S x S pairwise loss partials ----------------
__global__ void finalize_k(const float* __restrict__ sum1,
                           const float* __restrict__ sum2,
                           const unsigned* __restrict__ cnt,
                           const int* __restrict__ num,
                           float* __restrict__ partial) {
  __shared__ float m1[NS];
  __shared__ float m2[NS];
  __shared__ float red[256];
  const int b = blockIdx.x;
  const int j = threadIdx.x;

  unsigned c = cnt[b * NS + j];
  int nb = num[b];
  float v1 = 0.f, v2 = 0.f;
  if (j < nb && c > 0u) {
    float invc = 1.0f / (float)c;
    v1 = sum1[b * NS + j] * invc;
    v2 = sum2[b * NS + j] * invc;
  }
  m1[j] = v1; m2[j] = v2;
  __syncthreads();

  const float a1 = v1, a2 = v2;
  float accum = 0.f;
  #pragma unroll 8
  for (int k = 0; k < NS; ++k) {
    accum += fabsf(fabsf(a1 - m1[k]) - fabsf(a2 - m2[k]));
  }
  red[j] = accum;
  __syncthreads();
  for (int s = 128; s > 0; s >>= 1) {
    if (j < s) red[j] += red[j + s];
    __syncthreads();
  }
  if (j == 0) partial[b] = red[0];
}

// ---------------- K4: deterministic final reduce ----------------
__global__ void final_k(const float* __restrict__ partial, float* __restrict__ out) {
  if (threadIdx.x == 0 && blockIdx.x == 0) {
    float s = 0.f;
    for (int b = 0; b < NB; ++b) s += partial[b];
    out[0] = s / (float)((long long)NB * NS * NS);
  }
}

extern "C" void kernel_launch(void* const* d_in, const int* in_sizes, int n_in,
                              void* d_out, int out_size, void* d_ws, size_t ws_size,
                              hipStream_t stream) {
  const float* input   = (const float*)d_in[0];   // [8,64,256,256] f32
  const float* feature = (const float*)d_in[1];   // [8,64,64,64]   f32
  const int*   sp      = (const int*)d_in[2];     // [8,1,256,256]  int32 (harness)
  const int*   num     = (const int*)d_in[3];     // [8]            int32 (harness)
  float* out = (float*)d_out;

  // workspace layout (floats)
  float*    ws      = (float*)d_ws;
  float*    sum1    = ws;                     // 2048
  float*    sum2    = ws + 2048;              // 2048
  unsigned* cnt     = (unsigned*)(ws + 4096); // 2048
  float*    partial = ws + 6144;              // 8
  float*    fmean   = ws + 8192;              // 32768

  fmean_zero_k<<<129, 256, 0, stream>>>(feature, fmean, sum1, sum2, cnt);
  main_k<<<NB * BLKS_PER_IMG, 256, 0, stream>>>(input, sp, fmean, sum1, sum2, cnt);
  finalize_k<<<NB, 256, 0, stream>>>(sum1, sum2, cnt, num, partial);
  final_k<<<1, 64, 0, stream>>>(partial, out);
}

// Round 3
// 56.656 us; speedup vs baseline: 1.0730x; 1.0730x over previous
//
#include <hip/hip_runtime.h>

#define NB 8
#define NC 64
#define NH 256
#define NW 256
#define HW (NH*NW)
#define NFH 64
#define NFW 64
#define FHW (NFH*NFW)
#define NS 256
#define PPB 1024                 // pixels per block
#define NPB (HW/PPB)             // 64 pixel-blocks per image
#define NG 4                     // channel groups
#define CPG (NC/NG)              // 16 channels per group
#define NA (NB*NPB*NG)           // 2048 role-A blocks
#define NBB (NB*NPB)             // 512 role-B blocks

// ---------------- K1: feature channel-mean (float4 over pixels) ----------------
__global__ __launch_bounds__(256) void fmean_k(const float* __restrict__ feature,
                                               float* __restrict__ fmean) {
  int idx = blockIdx.x * 256 + threadIdx.x;     // 0..8191 (8 imgs * 1024 float4)
  int b = idx >> 10;
  int q = idx & 1023;                           // float4 index within image map
  const float4* src = reinterpret_cast<const float4*>(feature + (size_t)b * NC * FHW) + q;
  float4 a = make_float4(0.f, 0.f, 0.f, 0.f);
  #pragma unroll 16
  for (int c = 0; c < NC; ++c) {
    float4 v = src[(size_t)c * (FHW / 4)];
    a.x += v.x; a.y += v.y; a.z += v.z; a.w += v.w;
  }
  const float s = 1.0f / NC;
  a.x *= s; a.y *= s; a.z *= s; a.w *= s;
  reinterpret_cast<float4*>(fmean)[idx] = a;
}

// ---------------- K2: fused streaming kernel (role A: input hist, role B: cnt+feat hist) ----
__global__ __launch_bounds__(256) void
main_k(const float* __restrict__ input,
       const int* __restrict__ sp,
       const float* __restrict__ fmean,
       float* __restrict__ part1,     // [NA][NS]
       float* __restrict__ part2,     // [NBB][NS]
       float* __restrict__ partc) {   // [NBB][NS]
  __shared__ float s_f[FHW];          // 16 KB (role B only)
  __shared__ float s_bins[NS];
  __shared__ unsigned s_cnt[NS];

  const int bid = blockIdx.x;
  const int tid = threadIdx.x;

  if (bid < NA) {
    // ----- role A: channel-partial segment sums of input -----
    const int g  = bid & (NG - 1);
    const int pb = (bid >> 2) & (NPB - 1);
    const int b  = bid >> 8;

    s_bins[tid] = 0.f;
    __syncthreads();

    const int p0 = pb * PPB + tid * 4;
    const float* ib = input + ((size_t)(b * NC + g * CPG)) * HW + p0;
    float4 acc = make_float4(0.f, 0.f, 0.f, 0.f);
    #pragma unroll
    for (int c = 0; c < CPG; ++c) {
      float4 v = *reinterpret_cast<const float4*>(ib + (size_t)c * HW);
      acc.x += v.x; acc.y += v.y; acc.z += v.z; acc.w += v.w;
    }
    const float s = 1.0f / NC;
    int4 idv = *reinterpret_cast<const int4*>(sp + (size_t)b * HW + p0);
    atomicAdd(&s_bins[idv.x], acc.x * s);
    atomicAdd(&s_bins[idv.y], acc.y * s);
    atomicAdd(&s_bins[idv.z], acc.z * s);
    atomicAdd(&s_bins[idv.w], acc.w * s);
    __syncthreads();

    part1[(size_t)bid * NS + tid] = s_bins[tid];
  } else {
    // ----- role B: counts + bilinear feature-mean segment sums -----
    const int r  = bid - NA;          // 0..511
    const int b  = r >> 6;
    const int pb = r & (NPB - 1);

    const float4* fsrc = reinterpret_cast<const float4*>(fmean + (size_t)b * FHW);
    #pragma unroll
    for (int i = 0; i < 4; ++i)
      reinterpret_cast<float4*>(s_f)[tid + 256 * i] = fsrc[tid + 256 * i];
    s_bins[tid] = 0.f;
    s_cnt[tid] = 0u;
    __syncthreads();

    const int p0 = pb * PPB + tid * 4;
    int4 idv = *reinterpret_cast<const int4*>(sp + (size_t)b * HW + p0);
    int ids[4] = {idv.x, idv.y, idv.z, idv.w};

    // row (h) is shared by the thread's 4 pixels
    const int h = p0 >> 8;
    const float yd = (float)h * (63.0f / 255.0f);
    const int y0 = (int)yd;
    const float wy = yd - (float)y0;
    const int y1 = min(y0 + 1, NFH - 1);
    const float* row0 = s_f + y0 * NFW;
    const float* row1 = s_f + y1 * NFW;

    #pragma unroll
    for (int i = 0; i < 4; ++i) {
      const int w = (p0 & 255) + i;
      const float xd = (float)w * (63.0f / 255.0f);
      const int x0 = (int)xd;
      const float wx = xd - (float)x0;
      const int x1 = min(x0 + 1, NFW - 1);
      float top = row0[x0] * (1.f - wx) + row0[x1] * wx;
      float bot = row1[x0] * (1.f - wx) + row1[x1] * wx;
      float fv = top * (1.f - wy) + bot * wy;
      atomicAdd(&s_bins[ids[i]], fv);
      atomicAdd(&s_cnt[ids[i]], 1u);
    }
    __syncthreads();

    part2[(size_t)r * NS + tid] = s_bins[tid];
    partc[(size_t)r * NS + tid] = (float)s_cnt[tid];
  }
}

// ---------------- K3: reduce partials -> means -> S x S pairwise loss partial ----------------
__global__ __launch_bounds__(256) void
finalize_k(const float* __restrict__ part1,
           const float* __restrict__ part2,
           const float* __restrict__ partc,
           const int* __restrict__ num,
           float* __restrict__ partial) {
  __shared__ float m1[NS];
  __shared__ float m2[NS];
  __shared__ float red[256];
  const int b = blockIdx.x;
  const int j = threadIdx.x;

  float s1 = 0.f;
  const float* p1 = part1 + (size_t)b * 256 * NS + j;   // 256 role-A blocks per image
  #pragma unroll 8
  for (int t = 0; t < 256; ++t) s1 += p1[(size_t)t * NS];

  float s2 = 0.f, c = 0.f;
  const float* p2 = part2 + (size_t)b * 64 * NS + j;
  const float* pc = partc + (size_t)b * 64 * NS + j;
  #pragma unroll 8
  for (int t = 0; t < 64; ++t) { s2 += p2[(size_t)t * NS]; c += pc[(size_t)t * NS]; }

  const int nb = num[b];
  float v1 = 0.f, v2 = 0.f;
  if (j < nb && c > 0.f) {
    float invc = 1.0f / c;
    v1 = s1 * invc;
    v2 = s2 * invc;
  }
  m1[j] = v1; m2[j] = v2;
  __syncthreads();

  float accum = 0.f;
  #pragma unroll 8
  for (int k = 0; k < NS; ++k) {
    accum += fabsf(fabsf(v1 - m1[k]) - fabsf(v2 - m2[k]));
  }
  red[j] = accum;
  __syncthreads();
  for (int s = 128; s > 0; s >>= 1) {
    if (j < s) red[j] += red[j + s];
    __syncthreads();
  }
  if (j == 0) partial[b] = red[0];
}

// ---------------- K4: deterministic final reduce ----------------
__global__ void final_k(const float* __restrict__ partial, float* __restrict__ out) {
  if (threadIdx.x == 0 && blockIdx.x == 0) {
    float s = 0.f;
    for (int b = 0; b < NB; ++b) s += partial[b];
    out[0] = s / (float)((long long)NB * NS * NS);
  }
}

extern "C" void kernel_launch(void* const* d_in, const int* in_sizes, int n_in,
                              void* d_out, int out_size, void* d_ws, size_t ws_size,
                              hipStream_t stream) {
  const float* input   = (const float*)d_in[0];   // [8,64,256,256] f32
  const float* feature = (const float*)d_in[1];   // [8,64,64,64]   f32
  const int*   sp      = (const int*)d_in[2];     // [8,1,256,256]  int32
  const int*   num     = (const int*)d_in[3];     // [8]            int32
  float* out = (float*)d_out;

  float* ws      = (float*)d_ws;
  float* part1   = ws;                            // NA*NS   = 524288 floats (2 MB)
  float* part2   = ws + (size_t)NA * NS;          // 131072 floats
  float* partc   = part2 + (size_t)NBB * NS;      // 131072 floats
  float* fmean   = partc + (size_t)NBB * NS;      // 32768 floats
  float* partial = fmean + NB * FHW;              // 8 floats

  fmean_k<<<32, 256, 0, stream>>>(feature, fmean);
  main_k<<<NA + NBB, 256, 0, stream>>>(input, sp, fmean, part1, part2, partc);
  finalize_k<<<NB, 256, 0, stream>>>(part1, part2, partc, num, partial);
  final_k<<<1, 64, 0, stream>>>(partial, out);
}